// Round 17
// baseline (261.170 us; speedup 1.0000x reference)
//
#include <hip/hip_runtime.h>
#include <math.h>

// loss = sum_q softmax-weighted avg of w_k, per ragged segment.
//   s2_qk = 1.25*log2(e) * dot(t1[q], t1[k])   (exp2 domain)
//   w_k   = 10 * rowsum(t1[k])
// seg0: q [0,4096),     k [0,2048)
// seg1: q [4096,10240), k [2048,10240)
// R17 = R10's measured-best attn (fixed-ref softmax, role-split, frag-major
// hi/lo K, atomic Z/Nm, (256,3) no-spill) fused into ONE NORMAL dispatch with
// a software grid barrier (no cooperative API):
//   grid 768 = 3 blocks/CU x 256 CU at (256,3) -> all co-resident, spin-safe.
//   barrier cnts in ws, zeroed per replay by hipMemsetAsync (capture-safe);
//   release __threadfence before arrive + agent-scope acquire on spin exit
//   handles per-XCD L2 non-coherence.
// phase1 prep (blocks 0..319) -> bar -> phase2 attn (FULL on slots %8==0,
// 2688 scans on the rest, 512 leftover scans second-pass on odd blocks)
// -> bar -> phase3 reduce (blocks 0..39).

#define T_ROWS 10240
#define SCALE2   1.80336880f   // 1.25 * log2(e)
#define INV_S2   0.55451774f   // 1 / SCALE2
#define SKIP_THR 35.0f         // exp2-domain skip margin
#define NBLK     768

typedef __bf16 bf16x8 __attribute__((ext_vector_type(8)));
typedef float  f32x16 __attribute__((ext_vector_type(16)));
typedef float  f32x4v __attribute__((ext_vector_type(4)));

__device__ __forceinline__ float ex2(float x) {
    return __builtin_amdgcn_exp2f(x);   // v_exp_f32: 2^x
}

__device__ __forceinline__ float max16(const f32x16& a) {
    float h0 = fmaxf(fmaxf(a[0],  a[1]),  fmaxf(a[2],  a[3]));
    float h1 = fmaxf(fmaxf(a[4],  a[5]),  fmaxf(a[6],  a[7]));
    float h2 = fmaxf(fmaxf(a[8],  a[9]),  fmaxf(a[10], a[11]));
    float h3 = fmaxf(fmaxf(a[12], a[13]), fmaxf(a[14], a[15]));
    return fmaxf(fmaxf(h0, h1), fmaxf(h2, h3));
}

// software grid barrier: all NBLK blocks co-resident by construction.
__device__ __forceinline__ void grid_barrier(int* cnt, int target) {
    __syncthreads();
    if (threadIdx.x == 0) {
        __threadfence();   // release: prior writes -> coherent point
        __hip_atomic_fetch_add(cnt, 1, __ATOMIC_ACQ_REL, __HIP_MEMORY_SCOPE_AGENT);
        while (__hip_atomic_load(cnt, __ATOMIC_ACQUIRE,
                                 __HIP_MEMORY_SCOPE_AGENT) < target)
            __builtin_amdgcn_s_sleep(8);
        __threadfence();   // acquire: invalidate stale local cache lines
    }
    __syncthreads();
}

// ---------------------------------------------------------------- FULL unit
// 64 q rows x 256 k rows (8 tiles), always-exp, two-chain body (R10 verbatim).
__device__ __forceinline__
void do_full(int f, int lane, int l31, int lhalf,
             const __bf16* __restrict__ khi, const __bf16* __restrict__ klo,
             const float* __restrict__ w, const float* __restrict__ selfs,
             float* __restrict__ Znm) {
    int qb, kt0; bool use_self;
    if (f < 32)       { qb = f * 64;                kt0 = (f >> 2) * 8;          use_self = true;  }
    else if (f < 288) { int i = f - 32; qb = 2048 + (i >> 3) * 64; kt0 = (i & 7) * 8; use_self = false; }
    else              { int j = f - 288; qb = 4096 + j * 64; kt0 = 64 + (8 + (j >> 2)) * 8; use_self = true; }

    #pragma unroll 1
    for (int s = 0; s < 2; ++s) {
        const int rb = (qb >> 5) + s;
        const __bf16* qp  = khi + (size_t)rb * 2048 + lane * 8;
        const __bf16* qlp = klo + (size_t)rb * 2048 + lane * 8;
        bf16x8 qh[4], ql[4];
        #pragma unroll
        for (int st = 0; st < 4; ++st) {
            qh[st] = *(const bf16x8*)(qp  + st * 512);
            ql[st] = *(const bf16x8*)(qlp + st * 512);
        }
        const int qrow = qb + s * 32 + l31;
        const float mref = use_self ? selfs[qrow] : 0.f;
        float z0 = 0.f, z1 = 0.f, z2 = 0.f, z3 = 0.f;
        float n0 = 0.f, n1 = 0.f, n2 = 0.f, n3 = 0.f;

        #pragma unroll 1
        for (int t = 0; t < 8; ++t) {
            f32x16 p, c;
            #pragma unroll
            for (int r = 0; r < 16; ++r) { p[r] = 0.f; c[r] = 0.f; }
            {   // kh live region: p-chain (hh) and c's kh*ql part
                const __bf16* kp = khi + (size_t)(kt0 + t) * 2048 + lane * 8;
                bf16x8 kh[4];
                #pragma unroll
                for (int st = 0; st < 4; ++st)
                    kh[st] = *(const bf16x8*)(kp + st * 512);
                #pragma unroll
                for (int st = 0; st < 4; ++st)
                    p = __builtin_amdgcn_mfma_f32_32x32x16_bf16(kh[st], qh[st], p, 0, 0, 0);
                #pragma unroll
                for (int st = 0; st < 4; ++st)
                    c = __builtin_amdgcn_mfma_f32_32x32x16_bf16(kh[st], ql[st], c, 0, 0, 0);
            }   // kh dead here
            {   // kl live region (reuses kh's registers)
                const __bf16* klp = klo + (size_t)(kt0 + t) * 2048 + lane * 8;
                bf16x8 kl[4];
                #pragma unroll
                for (int st = 0; st < 4; ++st)
                    kl[st] = *(const bf16x8*)(klp + st * 512);
                #pragma unroll
                for (int st = 0; st < 4; ++st)
                    c = __builtin_amdgcn_mfma_f32_32x32x16_bf16(kl[st], qh[st], c, 0, 0, 0);
            }
            const float* wp = w + (kt0 + t) * 32 + lhalf * 4;
            #pragma unroll
            for (int g = 0; g < 4; ++g) {
                f32x4v wv4 = *(const f32x4v*)(wp + g * 8);
                float e0 = ex2(fmaf(c[g*4],   SCALE2, fmaf(p[g*4],   SCALE2, -mref)));
                float e1 = ex2(fmaf(c[g*4+1], SCALE2, fmaf(p[g*4+1], SCALE2, -mref)));
                float e2 = ex2(fmaf(c[g*4+2], SCALE2, fmaf(p[g*4+2], SCALE2, -mref)));
                float e3 = ex2(fmaf(c[g*4+3], SCALE2, fmaf(p[g*4+3], SCALE2, -mref)));
                z0 += e0; z1 += e1; z2 += e2; z3 += e3;
                n0 = fmaf(e0, wv4[0], n0);
                n1 = fmaf(e1, wv4[1], n1);
                n2 = fmaf(e2, wv4[2], n2);
                n3 = fmaf(e3, wv4[3], n3);
            }
        }
        float Z = (z0 + z1) + (z2 + z3);
        float N = (n0 + n1) + (n2 + n3);
        Z += __shfl(Z, lane ^ 32);          // same mref both halves: plain add
        N += __shfl(N, lane ^ 32);
        if (lhalf == 0) {
            atomicAdd(&Znm[2 * qrow],     Z);
            atomicAdd(&Znm[2 * qrow + 1], N);
        }
    }
}

// ---------------------------------------------------------------- SCAN unit
// 64 q rows x 256 k rows (8 tiles): hh + fixed-threshold skip (R10 verbatim).
__device__ __forceinline__
void do_scan(int idx, int lane, int l31, int lhalf,
             const __bf16* __restrict__ khi, const __bf16* __restrict__ klo,
             const float* __restrict__ w, const float* __restrict__ selfs,
             float* __restrict__ Znm) {
    int qb, kt0;
    if (idx < 224) {
        int qw = idx / 7, cp = idx % 7, cd = qw >> 2;
        int c = cp + (cp >= cd);
        qb = qw * 64; kt0 = c * 8;
    } else {
        int i = idx - 224;
        int qw = i / 31, cp = i % 31, cd = 8 + (qw >> 2);
        int c = cp + (cp >= cd);
        qb = 4096 + qw * 64; kt0 = 64 + c * 8;
    }

    const int rb = qb >> 5;
    bf16x8 qh0[4], qh1[4];
    {
        const __bf16* q0 = khi + (size_t)rb * 2048 + lane * 8;
        #pragma unroll
        for (int st = 0; st < 4; ++st) {
            qh0[st] = *(const bf16x8*)(q0 + st * 512);
            qh1[st] = *(const bf16x8*)(q0 + 2048 + st * 512);
        }
    }
    const int qr0 = qb + l31, qr1 = qb + 32 + l31;
    const float mr0 = selfs[qr0], mr1 = selfs[qr1];
    const float th0 = (mr0 - SKIP_THR) * INV_S2;   // raw-score threshold
    const float th1 = (mr1 - SKIP_THR) * INV_S2;
    float Z0 = 0.f, N0 = 0.f, Z1 = 0.f, N1 = 0.f;

    // cold survivor (~never taken): c = p (C-in), sequenced ql -> kl loads
    auto cold = [&](float& Zr, float& Nr, const bf16x8 (&qhs)[4],
                    int rbs, float mref, int t,
                    const f32x16& p, const bf16x8 (&kh)[4]) {
        f32x16 c = p;
        {
            const __bf16* qlp = klo + (size_t)rbs * 2048 + lane * 8;
            bf16x8 ql[4];
            #pragma unroll
            for (int st = 0; st < 4; ++st)
                ql[st] = *(const bf16x8*)(qlp + st * 512);
            #pragma unroll
            for (int st = 0; st < 4; ++st)
                c = __builtin_amdgcn_mfma_f32_32x32x16_bf16(kh[st], ql[st], c, 0, 0, 0);
        }
        {
            const __bf16* klp = klo + (size_t)(kt0 + t) * 2048 + lane * 8;
            bf16x8 kl[4];
            #pragma unroll
            for (int st = 0; st < 4; ++st)
                kl[st] = *(const bf16x8*)(klp + st * 512);
            #pragma unroll
            for (int st = 0; st < 4; ++st)
                c = __builtin_amdgcn_mfma_f32_32x32x16_bf16(kl[st], qhs[st], c, 0, 0, 0);
        }
        const float* wp = w + (kt0 + t) * 32 + lhalf * 4;
        float z0 = 0.f, z1 = 0.f, z2 = 0.f, z3 = 0.f;
        float n0 = 0.f, n1 = 0.f, n2 = 0.f, n3 = 0.f;
        #pragma unroll
        for (int g = 0; g < 4; ++g) {
            f32x4v wv4 = *(const f32x4v*)(wp + g * 8);
            float e0 = ex2(fmaf(c[g*4],   SCALE2, -mref));
            float e1 = ex2(fmaf(c[g*4+1], SCALE2, -mref));
            float e2 = ex2(fmaf(c[g*4+2], SCALE2, -mref));
            float e3 = ex2(fmaf(c[g*4+3], SCALE2, -mref));
            z0 += e0; z1 += e1; z2 += e2; z3 += e3;
            n0 = fmaf(e0, wv4[0], n0);
            n1 = fmaf(e1, wv4[1], n1);
            n2 = fmaf(e2, wv4[2], n2);
            n3 = fmaf(e3, wv4[3], n3);
        }
        Zr += (z0 + z1) + (z2 + z3);
        Nr += (n0 + n1) + (n2 + n3);
    };

    bf16x8 kb0[4], kb1[4];
    {
        const __bf16* kp = khi + (size_t)kt0 * 2048 + lane * 8;
        #pragma unroll
        for (int st = 0; st < 4; ++st) {
            kb0[st] = *(const bf16x8*)(kp + st * 512);
            kb1[st] = *(const bf16x8*)(kp + 2048 + st * 512);
        }
    }

    #pragma unroll 1
    for (int t = 0; t < 8; t += 2) {
        {   // ---- tile t on kb0 ----
            f32x16 p0;
            #pragma unroll
            for (int r = 0; r < 16; ++r) p0[r] = 0.f;
            #pragma unroll
            for (int st = 0; st < 4; ++st)
                p0 = __builtin_amdgcn_mfma_f32_32x32x16_bf16(kb0[st], qh0[st], p0, 0, 0, 0);
            if (!__all(max16(p0) <= th0)) cold(Z0, N0, qh0, rb,     mr0, t, p0, kb0);
            f32x16 p1;
            #pragma unroll
            for (int r = 0; r < 16; ++r) p1[r] = 0.f;
            #pragma unroll
            for (int st = 0; st < 4; ++st)
                p1 = __builtin_amdgcn_mfma_f32_32x32x16_bf16(kb0[st], qh1[st], p1, 0, 0, 0);
            if (!__all(max16(p1) <= th1)) cold(Z1, N1, qh1, rb + 1, mr1, t, p1, kb0);
            int pf = (t + 2 < 8) ? t + 2 : t;
            const __bf16* kp = khi + (size_t)(kt0 + pf) * 2048 + lane * 8;
            #pragma unroll
            for (int st = 0; st < 4; ++st)
                kb0[st] = *(const bf16x8*)(kp + st * 512);
        }
        {   // ---- tile t+1 on kb1 ----
            f32x16 p0;
            #pragma unroll
            for (int r = 0; r < 16; ++r) p0[r] = 0.f;
            #pragma unroll
            for (int st = 0; st < 4; ++st)
                p0 = __builtin_amdgcn_mfma_f32_32x32x16_bf16(kb1[st], qh0[st], p0, 0, 0, 0);
            if (!__all(max16(p0) <= th0)) cold(Z0, N0, qh0, rb,     mr0, t + 1, p0, kb1);
            f32x16 p1;
            #pragma unroll
            for (int r = 0; r < 16; ++r) p1[r] = 0.f;
            #pragma unroll
            for (int st = 0; st < 4; ++st)
                p1 = __builtin_amdgcn_mfma_f32_32x32x16_bf16(kb1[st], qh1[st], p1, 0, 0, 0);
            if (!__all(max16(p1) <= th1)) cold(Z1, N1, qh1, rb + 1, mr1, t + 1, p1, kb1);
            int pf = (t + 3 < 8) ? t + 3 : t + 1;
            const __bf16* kp = khi + (size_t)(kt0 + pf) * 2048 + lane * 8;
            #pragma unroll
            for (int st = 0; st < 4; ++st)
                kb1[st] = *(const bf16x8*)(kp + st * 512);
        }
    }

    Z0 += __shfl(Z0, lane ^ 32); N0 += __shfl(N0, lane ^ 32);
    Z1 += __shfl(Z1, lane ^ 32); N1 += __shfl(N1, lane ^ 32);
    if (lhalf == 0) {
        atomicAdd(&Znm[2 * qr0],     Z0);
        atomicAdd(&Znm[2 * qr0 + 1], N0);
        atomicAdd(&Znm[2 * qr1],     Z1);
        atomicAdd(&Znm[2 * qr1 + 1], N1);
    }
}

// ---------------------------------------------------------------- fused
__global__ __launch_bounds__(256, 3)
void fused_kernel(const float* __restrict__ base,
                  __bf16* __restrict__ khi, __bf16* __restrict__ klo,
                  float* __restrict__ w, float* __restrict__ selfs,
                  float* __restrict__ Znm, float* __restrict__ out,
                  int* __restrict__ cnt) {
    __shared__ float red[256];
    const int tid = threadIdx.x;
    const int bid = blockIdx.x;

    // ---------------- phase 1: prep (blocks 0..319) ----------------
    if (bid < 320) {
        if (tid < 64) Znm[bid * 64 + tid] = 0.f;   // 320*64 = 20480

        int row = bid * 32 + (tid >> 3);
        int c0  = (tid & 7) << 3;
        const float* p = base + (size_t)row * 64 + c0;
        f32x4v a = *(const f32x4v*)p;
        f32x4v b = *(const f32x4v*)(p + 4);

        float sum = ((a[0] + a[1]) + (a[2] + a[3])) + ((b[0] + b[1]) + (b[2] + b[3]));
        float sq = a[0] * a[0];
        sq = fmaf(a[1], a[1], sq); sq = fmaf(a[2], a[2], sq); sq = fmaf(a[3], a[3], sq);
        sq = fmaf(b[0], b[0], sq); sq = fmaf(b[1], b[1], sq);
        sq = fmaf(b[2], b[2], sq); sq = fmaf(b[3], b[3], sq);
        #pragma unroll
        for (int off = 1; off < 8; off <<= 1) {
            sum += __shfl_xor(sum, off);
            sq  += __shfl_xor(sq, off);
        }
        if ((tid & 7) == 0) { w[row] = 10.0f * sum; selfs[row] = SCALE2 * sq; }

        bf16x8 h, l;
        #pragma unroll
        for (int j = 0; j < 4; ++j) {
            __bf16 h0 = (__bf16)a[j];
            h[j] = h0; l[j] = (__bf16)(a[j] - (float)h0);
            __bf16 h1 = (__bf16)b[j];
            h[j + 4] = h1; l[j + 4] = (__bf16)(b[j] - (float)h1);
        }
        int kt = row >> 5, lr = row & 31;
        int st = c0 >> 4, lh = (c0 >> 3) & 1;
        size_t dst = (size_t)kt * 2048 + st * 512 + lh * 256 + lr * 8;
        *(bf16x8*)(khi + dst) = h;
        *(bf16x8*)(klo + dst) = l;
    }

    grid_barrier(cnt + 0, NBLK);

    // ---------------- phase 2: attn units on wave-slots ----------------
    const int lane  = tid & 63;
    const int l31   = lane & 31;
    const int lhalf = lane >> 5;
    const int slot  = bid * 4 + (tid >> 6);   // 0..3071

    if ((slot & 7) == 0)
        do_full(slot >> 3, lane, l31, lhalf, khi, klo, w, selfs, Znm);
    else
        do_scan(slot - (slot >> 3) - 1, lane, l31, lhalf, khi, klo, w, selfs, Znm);

    if (bid & 1) {                             // second pass: odd blocks
        int rank = (bid >> 1) * 4 + (tid >> 6);
        if (rank < 512)
            do_scan(2688 + rank, lane, l31, lhalf, khi, klo, w, selfs, Znm);
    }

    grid_barrier(cnt + 1, NBLK);

    // ---------------- phase 3: reduce (blocks 0..39) ----------------
    if (bid < 40) {
        int gq = bid * 256 + tid;
        red[tid] = Znm[2 * gq + 1] / Znm[2 * gq];
        __syncthreads();
        #pragma unroll
        for (int s = 128; s > 0; s >>= 1) {
            if (tid < s) red[tid] += red[tid + s];
            __syncthreads();
        }
        if (tid == 0) atomicAdd(out, red[0]);
    }
}

// ----------------------------------------------------------------- launch
extern "C" void kernel_launch(void* const* d_in, const int* in_sizes, int n_in,
                              void* d_out, int out_size, void* d_ws, size_t ws_size,
                              hipStream_t stream) {
    const float* base = (const float*)d_in[0];
    float* out = (float*)d_out;
    float* ws  = (float*)d_ws;

    float*  w     = ws;                           // 10240 f32
    float*  selfs = ws + T_ROWS;                  // 10240 f32
    float*  Znm   = ws + 2 * T_ROWS;              // 20480 f32
    __bf16* khi   = (__bf16*)(ws + 4 * T_ROWS);   // 320*2048 bf16
    __bf16* klo   = khi + 320 * 2048;
    int*    cnt   = (int*)(klo + 320 * 2048);     // 2 barrier counters

    (void)hipMemsetAsync(d_out, 0, sizeof(float), stream);
    (void)hipMemsetAsync(cnt, 0, 2 * sizeof(int), stream);
    fused_kernel<<<NBLK, 256, 0, stream>>>(base, khi, klo, w, selfs, Znm, out, cnt);
}

// Round 18
// 27.998 us; speedup vs baseline: 9.3282x; 9.3282x over previous
//
#include <hip/hip_runtime.h>
#include <math.h>

// loss = sum_q softmax-weighted avg of w_k, per ragged segment.
//   s2_qk = 1.25*log2(e) * dot(t1[q], t1[k])   (exp2 domain)
//   w_k   = 10 * rowsum(t1[k])
// seg0: q [0,4096),     k [0,2048)
// seg1: q [4096,10240), k [2048,10240)
// R18 = R10 verbatim — the session's measured-best kernel (28.1 us).
// Fixed-reference softmax: m_ref = selfs[q] (self-seeded rows) or 0
// (seg0 rows 2048..4096). Exact math (ratio invariant), no online max, no
// rescale, cross-block merge = atomicAdd(Z)/atomicAdd(Nm). Role-split waves:
// 384 FULL waves (diag chunks + no-self rows; straight-line hh+corr+exp,
// dispatched first), 3200 SCAN waves (hh + fixed-threshold test; cold
// survivor path). No LDS, no barriers, frag-major K/Q (hi/lo bf16 split).
// (256,3): 168-VGPR budget -> no scratch spills (the R9->R10 13-us lever).
// Subsequent falsified variants: C-in fusion (R11 30.4), occupancy-4 (R12
// 29.6), rebalance (R13 35.3), branchless (R15 30.6), de-phase (R16 28.4),
// single-dispatch fusion (R14 fail, R17 261).

#define T_ROWS 10240
#define SCALE2   1.80336880f   // 1.25 * log2(e)
#define INV_S2   0.55451774f   // 1 / SCALE2
#define SKIP_THR 35.0f         // exp2-domain skip margin

typedef __bf16 bf16x8 __attribute__((ext_vector_type(8)));
typedef float  f32x16 __attribute__((ext_vector_type(16)));
typedef float  f32x4v __attribute__((ext_vector_type(4)));

__device__ __forceinline__ float ex2(float x) {
    return __builtin_amdgcn_exp2f(x);   // v_exp_f32: 2^x
}

__device__ __forceinline__ float max16(const f32x16& a) {
    float h0 = fmaxf(fmaxf(a[0],  a[1]),  fmaxf(a[2],  a[3]));
    float h1 = fmaxf(fmaxf(a[4],  a[5]),  fmaxf(a[6],  a[7]));
    float h2 = fmaxf(fmaxf(a[8],  a[9]),  fmaxf(a[10], a[11]));
    float h3 = fmaxf(fmaxf(a[12], a[13]), fmaxf(a[14], a[15]));
    return fmaxf(fmaxf(h0, h1), fmaxf(h2, h3));
}

// ---------------------------------------------------------------- prep
// Frag-major hi/lo split + w + selfs; zeroes Znm and out.
// lane=lhalf*32+l31 holds row 32*kt+l31, dims [st*16+lhalf*8, +8):
// khi[kt*2048 + st*512 + lh*256 + lr*8].
__global__ __launch_bounds__(256)
void prep_kernel(const float* __restrict__ base, __bf16* __restrict__ khi,
                 __bf16* __restrict__ klo, float* __restrict__ w,
                 float* __restrict__ selfs, float* __restrict__ Znm,
                 float* __restrict__ out) {
    int tid = threadIdx.x;
    if (blockIdx.x == 0 && tid == 0) *out = 0.f;
    if (tid < 64) Znm[blockIdx.x * 64 + tid] = 0.f;   // 320*64 = 20480

    int row = blockIdx.x * 32 + (tid >> 3);
    int c0  = (tid & 7) << 3;
    const float* p = base + (size_t)row * 64 + c0;
    f32x4v a = *(const f32x4v*)p;
    f32x4v b = *(const f32x4v*)(p + 4);

    float sum = ((a[0] + a[1]) + (a[2] + a[3])) + ((b[0] + b[1]) + (b[2] + b[3]));
    float sq = a[0] * a[0];
    sq = fmaf(a[1], a[1], sq); sq = fmaf(a[2], a[2], sq); sq = fmaf(a[3], a[3], sq);
    sq = fmaf(b[0], b[0], sq); sq = fmaf(b[1], b[1], sq);
    sq = fmaf(b[2], b[2], sq); sq = fmaf(b[3], b[3], sq);
    #pragma unroll
    for (int off = 1; off < 8; off <<= 1) {
        sum += __shfl_xor(sum, off);
        sq  += __shfl_xor(sq, off);
    }
    if ((tid & 7) == 0) { w[row] = 10.0f * sum; selfs[row] = SCALE2 * sq; }

    bf16x8 h, l;
    #pragma unroll
    for (int j = 0; j < 4; ++j) {
        __bf16 h0 = (__bf16)a[j];
        h[j] = h0; l[j] = (__bf16)(a[j] - (float)h0);
        __bf16 h1 = (__bf16)b[j];
        h[j + 4] = h1; l[j + 4] = (__bf16)(b[j] - (float)h1);
    }
    int kt = row >> 5, lr = row & 31;
    int st = c0 >> 4, lh = (c0 >> 3) & 1;
    size_t dst = (size_t)kt * 2048 + st * 512 + lh * 256 + lr * 8;
    *(bf16x8*)(khi + dst) = h;
    *(bf16x8*)(klo + dst) = l;
}

// ---------------------------------------------------------------- attn
// One wave = 64 q rows x 256 k rows (8 tiles). Waves 0..383 FULL, rest SCAN.
__global__ __launch_bounds__(256, 3)
void attn_kernel(const __bf16* __restrict__ khi, const __bf16* __restrict__ klo,
                 const float* __restrict__ w, const float* __restrict__ selfs,
                 float* __restrict__ Znm) {
    const int lane  = threadIdx.x & 63;
    const int l31   = lane & 31;
    const int lhalf = lane >> 5;
    const int wv    = blockIdx.x * 4 + (threadIdx.x >> 6);

    if (wv < 384) {
        // ================= FULL waves: always exp, straight-line =========
        int qb, kt0; bool use_self;
        if (wv < 32)       { qb = wv * 64;                kt0 = (wv >> 2) * 8;          use_self = true;  }
        else if (wv < 288) { int i = wv - 32; qb = 2048 + (i >> 3) * 64; kt0 = (i & 7) * 8; use_self = false; }
        else               { int j = wv - 288; qb = 4096 + j * 64; kt0 = 64 + (8 + (j >> 2)) * 8; use_self = true; }

        #pragma unroll 1
        for (int s = 0; s < 2; ++s) {
            const int rb = (qb >> 5) + s;
            const __bf16* qp  = khi + (size_t)rb * 2048 + lane * 8;
            const __bf16* qlp = klo + (size_t)rb * 2048 + lane * 8;
            bf16x8 qh[4], ql[4];
            #pragma unroll
            for (int st = 0; st < 4; ++st) {
                qh[st] = *(const bf16x8*)(qp  + st * 512);
                ql[st] = *(const bf16x8*)(qlp + st * 512);
            }
            const int qrow = qb + s * 32 + l31;
            const float mref = use_self ? selfs[qrow] : 0.f;
            float z0 = 0.f, z1 = 0.f, z2 = 0.f, z3 = 0.f;
            float n0 = 0.f, n1 = 0.f, n2 = 0.f, n3 = 0.f;

            #pragma unroll 1
            for (int t = 0; t < 8; ++t) {
                f32x16 p, c;
                #pragma unroll
                for (int r = 0; r < 16; ++r) { p[r] = 0.f; c[r] = 0.f; }
                {   // kh live region: p-chain and c's kh*ql part
                    const __bf16* kp = khi + (size_t)(kt0 + t) * 2048 + lane * 8;
                    bf16x8 kh[4];
                    #pragma unroll
                    for (int st = 0; st < 4; ++st)
                        kh[st] = *(const bf16x8*)(kp + st * 512);
                    #pragma unroll
                    for (int st = 0; st < 4; ++st)
                        p = __builtin_amdgcn_mfma_f32_32x32x16_bf16(kh[st], qh[st], p, 0, 0, 0);
                    #pragma unroll
                    for (int st = 0; st < 4; ++st)
                        c = __builtin_amdgcn_mfma_f32_32x32x16_bf16(kh[st], ql[st], c, 0, 0, 0);
                }   // kh dead here
                {   // kl live region (reuses kh's registers)
                    const __bf16* klp = klo + (size_t)(kt0 + t) * 2048 + lane * 8;
                    bf16x8 kl[4];
                    #pragma unroll
                    for (int st = 0; st < 4; ++st)
                        kl[st] = *(const bf16x8*)(klp + st * 512);
                    #pragma unroll
                    for (int st = 0; st < 4; ++st)
                        c = __builtin_amdgcn_mfma_f32_32x32x16_bf16(kl[st], qh[st], c, 0, 0, 0);
                }
                const float* wp = w + (kt0 + t) * 32 + lhalf * 4;
                #pragma unroll
                for (int g = 0; g < 4; ++g) {
                    f32x4v wv4 = *(const f32x4v*)(wp + g * 8);
                    float e0 = ex2(fmaf(c[g*4],   SCALE2, fmaf(p[g*4],   SCALE2, -mref)));
                    float e1 = ex2(fmaf(c[g*4+1], SCALE2, fmaf(p[g*4+1], SCALE2, -mref)));
                    float e2 = ex2(fmaf(c[g*4+2], SCALE2, fmaf(p[g*4+2], SCALE2, -mref)));
                    float e3 = ex2(fmaf(c[g*4+3], SCALE2, fmaf(p[g*4+3], SCALE2, -mref)));
                    z0 += e0; z1 += e1; z2 += e2; z3 += e3;
                    n0 = fmaf(e0, wv4[0], n0);
                    n1 = fmaf(e1, wv4[1], n1);
                    n2 = fmaf(e2, wv4[2], n2);
                    n3 = fmaf(e3, wv4[3], n3);
                }
            }
            float Z = (z0 + z1) + (z2 + z3);
            float N = (n0 + n1) + (n2 + n3);
            Z += __shfl(Z, lane ^ 32);          // same mref both halves: plain add
            N += __shfl(N, lane ^ 32);
            if (lhalf == 0) {
                atomicAdd(&Znm[2 * qrow],     Z);
                atomicAdd(&Znm[2 * qrow + 1], N);
            }
        }
    } else {
        // ================= SCAN waves: hh + fixed-threshold skip ==========
        int idx = wv - 384, qb, kt0;
        if (idx < 224) {
            int qw = idx / 7, cp = idx % 7, cd = qw >> 2;
            int c = cp + (cp >= cd);
            qb = qw * 64; kt0 = c * 8;
        } else {
            int i = idx - 224;
            int qw = i / 31, cp = i % 31, cd = 8 + (qw >> 2);
            int c = cp + (cp >= cd);
            qb = 4096 + qw * 64; kt0 = 64 + c * 8;
        }

        const int rb = qb >> 5;
        bf16x8 qh0[4], qh1[4];
        {
            const __bf16* q0 = khi + (size_t)rb * 2048 + lane * 8;
            #pragma unroll
            for (int st = 0; st < 4; ++st) {
                qh0[st] = *(const bf16x8*)(q0 + st * 512);
                qh1[st] = *(const bf16x8*)(q0 + 2048 + st * 512);
            }
        }
        const int qr0 = qb + l31, qr1 = qb + 32 + l31;
        const float mr0 = selfs[qr0], mr1 = selfs[qr1];
        const float th0 = (mr0 - SKIP_THR) * INV_S2;   // raw-score threshold
        const float th1 = (mr1 - SKIP_THR) * INV_S2;
        float Z0 = 0.f, N0 = 0.f, Z1 = 0.f, N1 = 0.f;

        // cold survivor: corr MFMAs (reuse staged kh) + fixed-ref exp
        auto cold = [&](float& Zr, float& Nr, const bf16x8 (&qhs)[4],
                        int rbs, float mref, int t,
                        const f32x16& p, const bf16x8 (&kh)[4]) {
            const __bf16* qlp = klo + (size_t)rbs * 2048 + lane * 8;
            const __bf16* klp = klo + (size_t)(kt0 + t) * 2048 + lane * 8;
            bf16x8 ql[4], kl[4];
            #pragma unroll
            for (int st = 0; st < 4; ++st) {
                ql[st] = *(const bf16x8*)(qlp + st * 512);
                kl[st] = *(const bf16x8*)(klp + st * 512);
            }
            f32x16 c;
            #pragma unroll
            for (int r = 0; r < 16; ++r) c[r] = 0.f;
            #pragma unroll
            for (int st = 0; st < 4; ++st) {
                c = __builtin_amdgcn_mfma_f32_32x32x16_bf16(kh[st], ql[st], c, 0, 0, 0);
                c = __builtin_amdgcn_mfma_f32_32x32x16_bf16(kl[st], qhs[st], c, 0, 0, 0);
            }
            const float* wp = w + (kt0 + t) * 32 + lhalf * 4;
            float z0 = 0.f, z1 = 0.f, z2 = 0.f, z3 = 0.f;
            float n0 = 0.f, n1 = 0.f, n2 = 0.f, n3 = 0.f;
            #pragma unroll
            for (int g = 0; g < 4; ++g) {
                f32x4v wv4 = *(const f32x4v*)(wp + g * 8);
                float e0 = ex2(fmaf(c[g*4],   SCALE2, fmaf(p[g*4],   SCALE2, -mref)));
                float e1 = ex2(fmaf(c[g*4+1], SCALE2, fmaf(p[g*4+1], SCALE2, -mref)));
                float e2 = ex2(fmaf(c[g*4+2], SCALE2, fmaf(p[g*4+2], SCALE2, -mref)));
                float e3 = ex2(fmaf(c[g*4+3], SCALE2, fmaf(p[g*4+3], SCALE2, -mref)));
                z0 += e0; z1 += e1; z2 += e2; z3 += e3;
                n0 = fmaf(e0, wv4[0], n0);
                n1 = fmaf(e1, wv4[1], n1);
                n2 = fmaf(e2, wv4[2], n2);
                n3 = fmaf(e3, wv4[3], n3);
            }
            Zr += (z0 + z1) + (z2 + z3);
            Nr += (n0 + n1) + (n2 + n3);
        };

        bf16x8 kb0[4], kb1[4];
        {
            const __bf16* kp = khi + (size_t)kt0 * 2048 + lane * 8;
            #pragma unroll
            for (int st = 0; st < 4; ++st) {
                kb0[st] = *(const bf16x8*)(kp + st * 512);
                kb1[st] = *(const bf16x8*)(kp + 2048 + st * 512);
            }
        }

        #pragma unroll 1
        for (int t = 0; t < 8; t += 2) {
            {   // ---- tile t on kb0 ----
                f32x16 p0;
                #pragma unroll
                for (int r = 0; r < 16; ++r) p0[r] = 0.f;
                #pragma unroll
                for (int st = 0; st < 4; ++st)
                    p0 = __builtin_amdgcn_mfma_f32_32x32x16_bf16(kb0[st], qh0[st], p0, 0, 0, 0);
                if (!__all(max16(p0) <= th0)) cold(Z0, N0, qh0, rb,     mr0, t, p0, kb0);
                f32x16 p1;
                #pragma unroll
                for (int r = 0; r < 16; ++r) p1[r] = 0.f;
                #pragma unroll
                for (int st = 0; st < 4; ++st)
                    p1 = __builtin_amdgcn_mfma_f32_32x32x16_bf16(kb0[st], qh1[st], p1, 0, 0, 0);
                if (!__all(max16(p1) <= th1)) cold(Z1, N1, qh1, rb + 1, mr1, t, p1, kb0);
                int pf = (t + 2 < 8) ? t + 2 : t;
                const __bf16* kp = khi + (size_t)(kt0 + pf) * 2048 + lane * 8;
                #pragma unroll
                for (int st = 0; st < 4; ++st)
                    kb0[st] = *(const bf16x8*)(kp + st * 512);
            }
            {   // ---- tile t+1 on kb1 ----
                f32x16 p0;
                #pragma unroll
                for (int r = 0; r < 16; ++r) p0[r] = 0.f;
                #pragma unroll
                for (int st = 0; st < 4; ++st)
                    p0 = __builtin_amdgcn_mfma_f32_32x32x16_bf16(kb1[st], qh0[st], p0, 0, 0, 0);
                if (!__all(max16(p0) <= th0)) cold(Z0, N0, qh0, rb,     mr0, t + 1, p0, kb1);
                f32x16 p1;
                #pragma unroll
                for (int r = 0; r < 16; ++r) p1[r] = 0.f;
                #pragma unroll
                for (int st = 0; st < 4; ++st)
                    p1 = __builtin_amdgcn_mfma_f32_32x32x16_bf16(kb1[st], qh1[st], p1, 0, 0, 0);
                if (!__all(max16(p1) <= th1)) cold(Z1, N1, qh1, rb + 1, mr1, t + 1, p1, kb1);
                int pf = (t + 3 < 8) ? t + 3 : t + 1;
                const __bf16* kp = khi + (size_t)(kt0 + pf) * 2048 + lane * 8;
                #pragma unroll
                for (int st = 0; st < 4; ++st)
                    kb1[st] = *(const bf16x8*)(kp + st * 512);
            }
        }

        Z0 += __shfl(Z0, lane ^ 32); N0 += __shfl(N0, lane ^ 32);
        Z1 += __shfl(Z1, lane ^ 32); N1 += __shfl(N1, lane ^ 32);
        if (lhalf == 0) {
            atomicAdd(&Znm[2 * qr0],     Z0);
            atomicAdd(&Znm[2 * qr0 + 1], N0);
            atomicAdd(&Znm[2 * qr1],     Z1);
            atomicAdd(&Znm[2 * qr1 + 1], N1);
        }
    }
}

// ---------------------------------------------------------------- reduce
__global__ void reduce_kernel(const float* __restrict__ Znm,
                              float* __restrict__ out) {
    __shared__ float red[256];
    int gq = blockIdx.x * 256 + threadIdx.x;
    float contrib = Znm[2 * gq + 1] / Znm[2 * gq];
    red[threadIdx.x] = contrib;
    __syncthreads();
    #pragma unroll
    for (int s = 128; s > 0; s >>= 1) {
        if (threadIdx.x < s) red[threadIdx.x] += red[threadIdx.x + s];
        __syncthreads();
    }
    if (threadIdx.x == 0) atomicAdd(out, red[0]);
}

// ----------------------------------------------------------------- launch
extern "C" void kernel_launch(void* const* d_in, const int* in_sizes, int n_in,
                              void* d_out, int out_size, void* d_ws, size_t ws_size,
                              hipStream_t stream) {
    const float* base = (const float*)d_in[0];
    float* out = (float*)d_out;
    float* ws  = (float*)d_ws;

    float*  w     = ws;                           // 10240 f32
    float*  selfs = ws + T_ROWS;                  // 10240 f32
    float*  Znm   = ws + 2 * T_ROWS;              // 20480 f32
    __bf16* khi   = (__bf16*)(ws + 4 * T_ROWS);   // 320*2048 bf16
    __bf16* klo   = khi + 320 * 2048;

    prep_kernel<<<T_ROWS / 32, 256, 0, stream>>>(base, khi, klo, w, selfs, Znm, out);
    // 3584 waves = 384 full (first) + 3200 scan; 4 waves/block -> 896 blocks
    attn_kernel<<<896, 256, 0, stream>>>(khi, klo, w, selfs, Znm);
    reduce_kernel<<<T_ROWS / 256, 256, 0, stream>>>(Znm, out);
}